// Round 1
// baseline (85.992 us; speedup 1.0000x reference)
//
#include <hip/hip_runtime.h>

// Problem constants (match reference file)
#define S_LEN 512
#define B_SZ  512
#define D_DIM 256
#define SEP_ID 13
#define PAD_ID 1

// Kernel 1: per-batch-column state machine over the sequence dimension.
// One thread per column b. Emits idx[s*B + b] = (skip ? -1 : s - pad_num).
__global__ void emb_scan_kernel(const int* __restrict__ seq,
                                int* __restrict__ idx) {
    int b = blockIdx.x * blockDim.x + threadIdx.x;
    if (b >= B_SZ) return;
    bool prev_sep = false;
    int pad_num = 0;
    for (int s = 0; s < S_LEN; ++s) {
        int tok = seq[s * B_SZ + b];           // coalesced across threads at each s
        bool is_sep = (tok == SEP_ID);
        // tok==PAD_ID and tok==SEP_ID are mutually exclusive, so the
        // reference's (prev_sep & tok==PAD & ~is_sep) reduces to:
        bool skip = prev_sep && (tok == PAD_ID);
        idx[s * B_SZ + b] = skip ? -1 : (s - pad_num);
        prev_sep = is_sep || skip;
        pad_num += skip ? 1 : 0;
    }
}

// Kernel 2: fused token-embedding gather + positional add.
// 64 lanes per (s,b) row; each lane writes one float4 of the D=256 row.
__global__ void emb_fused_kernel(const int* __restrict__ seq,
                                 const float* __restrict__ tw,
                                 const float* __restrict__ pe,
                                 const int* __restrict__ idx,
                                 float* __restrict__ out) {
    unsigned int t = blockIdx.x * blockDim.x + threadIdx.x;
    unsigned int row  = t >> 6;        // (s*B + b)
    unsigned int lane = t & 63u;       // 0..63, 4 floats each
    int tok  = seq[row];               // broadcast within the 64-lane group
    int pidx = idx[row];

    size_t doff = (size_t)lane * 4;
    float4 tv = *(const float4*)(tw + (size_t)tok * D_DIM + doff);
    float4 pv = make_float4(0.f, 0.f, 0.f, 0.f);
    if (pidx >= 0) {
        pv = *(const float4*)(pe + (size_t)pidx * D_DIM + doff);
    }
    float m = (tok != 0) ? 1.0f : 0.0f;
    float4 o;
    o.x = tv.x * m + pv.x;
    o.y = tv.y * m + pv.y;
    o.z = tv.z * m + pv.z;
    o.w = tv.w * m + pv.w;
    *(float4*)(out + (size_t)row * D_DIM + doff) = o;
}

extern "C" void kernel_launch(void* const* d_in, const int* in_sizes, int n_in,
                              void* d_out, int out_size, void* d_ws, size_t ws_size,
                              hipStream_t stream) {
    const int*   seq = (const int*)d_in[0];    // [S, B] int32
    const float* tw  = (const float*)d_in[1];  // [VOCAB, D] f32
    const float* pe  = (const float*)d_in[2];  // [MAX_LEN, D] f32
    float* out = (float*)d_out;                // [S, B, D] f32
    int*   idx = (int*)d_ws;                   // [S, B] int32 scratch (1 MiB)

    // 1) per-column scan: 512 threads
    emb_scan_kernel<<<dim3((B_SZ + 255) / 256), dim3(256), 0, stream>>>(seq, idx);

    // 2) fused gather+add: (S*B rows) * 64 lanes = 16,777,216 threads
    const unsigned int total_threads = (unsigned int)S_LEN * B_SZ * 64u;
    emb_fused_kernel<<<dim3(total_threads / 256), dim3(256), 0, stream>>>(
        seq, tw, pe, idx, out);
}

// Round 3
// 68.606 us; speedup vs baseline: 1.2534x; 1.2534x over previous
//
#include <hip/hip_runtime.h>

// Problem constants (match reference file)
#define S_LEN 512
#define B_SZ  512
#define D_DIM 256
#define SEP_ID 13
#define PAD_ID 1

#define NBLK   2048
#define NTHR   256
#define NGROUP ((NBLK * NTHR) / 64)               // 8192 row-groups (one wave each)
#define ROWS_PER_GROUP ((S_LEN * B_SZ) / NGROUP)  // 32

typedef float f32x4 __attribute__((ext_vector_type(4)));

// Kernel 1: wave-parallel inner-padding state machine.
// One wave per batch column. The recurrence p' = is_sep | (p & is_pad) is an
// associative transfer function f(p) = A | (p & B); we scan compositions
// across lanes (Kogge-Stone), recompute local skips with the incoming state,
// then prefix-sum skip counts for pad_num.
__global__ void emb_scan_wave(const int* __restrict__ seq,
                              int* __restrict__ idx) {
    const int lane = threadIdx.x & 63;
    const int b = blockIdx.x * (blockDim.x >> 6) + (threadIdx.x >> 6);
    if (b >= B_SZ) return;

    const int s0 = lane * (S_LEN / 64);      // 8 positions per lane
    int toks[8];
#pragma unroll
    for (int k = 0; k < 8; ++k) toks[k] = seq[(s0 + k) * B_SZ + b];

    // Local transfer function over this lane's 8 tokens: f(p) = A | (p & B)
    unsigned A = 0u, Bf = 1u;
#pragma unroll
    for (int k = 0; k < 8; ++k) {
        unsigned a  = (toks[k] == SEP_ID) ? 1u : 0u;
        unsigned bb = (toks[k] == PAD_ID) ? 1u : 0u;
        A  = a | (A & bb);
        Bf = Bf & bb;
    }

    // Inclusive Kogge-Stone scan of function composition (lower lanes first):
    // (g o f)(p) = g.A | (f.A & g.B) | (p & (f.B & g.B))
    unsigned incA = A, incB = Bf;
    for (int d = 1; d < 64; d <<= 1) {
        unsigned Al = __shfl_up(incA, d, 64);
        unsigned Bl = __shfl_up(incB, d, 64);
        if (lane >= d) {
            incA = incA | (Al & incB);
            incB = Bl & incB;
        }
    }
    // Incoming state for this lane = exclusive-scan A (p0 = false)
    unsigned pin = __shfl_up(incA, 1, 64);
    if (lane == 0) pin = 0u;

    // Recompute the 8 steps with the true incoming state
    unsigned p = pin, skipbits = 0u;
    int cnt = 0;
#pragma unroll
    for (int k = 0; k < 8; ++k) {
        unsigned a  = (toks[k] == SEP_ID) ? 1u : 0u;
        unsigned bb = (toks[k] == PAD_ID) ? 1u : 0u;
        unsigned skip = p & bb;
        skipbits |= skip << k;
        cnt += (int)skip;
        p = a | skip;
    }

    // Exclusive prefix sum of per-lane skip counts -> pad_num at lane start
    int pref = cnt;
    for (int d = 1; d < 64; d <<= 1) {
        int v = __shfl_up(pref, d, 64);
        if (lane >= d) pref += v;
    }
    pref -= cnt;

    int pad = pref;
#pragma unroll
    for (int k = 0; k < 8; ++k) {
        int s = s0 + k;
        unsigned skip = (skipbits >> k) & 1u;
        idx[s * B_SZ + b] = skip ? -1 : (s - pad);
        pad += (int)skip;
    }
}

// Kernel 2: fused token-embedding gather + positional add.
// 64 lanes per (s,b) row, one float4 per lane, 32 rows per wave (counted
// grid-stride) so the compiler can software-pipeline independent iterations.
__global__ void __launch_bounds__(NTHR)
emb_fused_kernel(const int* __restrict__ seq,
                 const float* __restrict__ tw,
                 const float* __restrict__ pe,
                 const int* __restrict__ idx,
                 float* __restrict__ out) {
    const unsigned t     = blockIdx.x * NTHR + threadIdx.x;
    const unsigned lane  = t & 63u;
    const unsigned group = t >> 6;
    const unsigned doff  = lane * 4u;

#pragma unroll 4
    for (int it = 0; it < ROWS_PER_GROUP; ++it) {
        const unsigned row = group + (unsigned)it * NGROUP;
        const int tok  = seq[row];
        const int pidx = idx[row];

        const f32x4 tv = *(const f32x4*)(tw + (size_t)tok * D_DIM + doff);
        const int    pc = (pidx < 0) ? 0 : pidx;
        const f32x4 pv = *(const f32x4*)(pe + (size_t)pc * D_DIM + doff);

        const float tm = (tok != 0) ? 1.0f : 0.0f;
        const float pm = (pidx < 0) ? 0.0f : 1.0f;

        f32x4 o;
        o.x = tv.x * tm + pv.x * pm;
        o.y = tv.y * tm + pv.y * pm;
        o.z = tv.z * tm + pv.z * pm;
        o.w = tv.w * tm + pv.w * pm;

        __builtin_nontemporal_store(o, (f32x4*)(out + (size_t)row * D_DIM + doff));
    }
}

extern "C" void kernel_launch(void* const* d_in, const int* in_sizes, int n_in,
                              void* d_out, int out_size, void* d_ws, size_t ws_size,
                              hipStream_t stream) {
    const int*   seq = (const int*)d_in[0];    // [S, B] int32
    const float* tw  = (const float*)d_in[1];  // [VOCAB, D] f32
    const float* pe  = (const float*)d_in[2];  // [MAX_LEN, D] f32
    float* out = (float*)d_out;                // [S, B, D] f32
    int*   idx = (int*)d_ws;                   // [S, B] int32 scratch (1 MiB)

    // 1) wave-parallel scan: 512 columns, 1 wave each -> 128 blocks x 256
    emb_scan_wave<<<dim3(B_SZ / 4), dim3(256), 0, stream>>>(seq, idx);

    // 2) fused gather+add
    emb_fused_kernel<<<dim3(NBLK), dim3(NTHR), 0, stream>>>(seq, tw, pe, idx, out);
}

// Round 4
// 59.184 us; speedup vs baseline: 1.4530x; 1.1592x over previous
//
#include <hip/hip_runtime.h>

// Problem constants (match reference file)
#define S_LEN 512
#define B_SZ  512
#define D_DIM 256
#define SEP_ID 13
#define PAD_ID 1

#define NTHR   256
#define ROWS_PER_WAVE 32
#define NROWS  (S_LEN * B_SZ)                         // 262144
#define NWAVE  (NROWS / ROWS_PER_WAVE)                // 8192 waves
#define NBLK   (NWAVE / (NTHR / 64))                  // 2048 blocks

typedef float f32x4 __attribute__((ext_vector_type(4)));

// Kernel 1: wave-parallel inner-padding state machine (unchanged from R3).
__global__ void emb_scan_wave(const int* __restrict__ seq,
                              int* __restrict__ idx) {
    const int lane = threadIdx.x & 63;
    const int b = blockIdx.x * (blockDim.x >> 6) + (threadIdx.x >> 6);
    if (b >= B_SZ) return;

    const int s0 = lane * (S_LEN / 64);      // 8 positions per lane
    int toks[8];
#pragma unroll
    for (int k = 0; k < 8; ++k) toks[k] = seq[(s0 + k) * B_SZ + b];

    // Local transfer function over this lane's 8 tokens: f(p) = A | (p & B)
    unsigned A = 0u, Bf = 1u;
#pragma unroll
    for (int k = 0; k < 8; ++k) {
        unsigned a  = (toks[k] == SEP_ID) ? 1u : 0u;
        unsigned bb = (toks[k] == PAD_ID) ? 1u : 0u;
        A  = a | (A & bb);
        Bf = Bf & bb;
    }

    // Inclusive Kogge-Stone scan of function composition (lower lanes first)
    unsigned incA = A, incB = Bf;
    for (int d = 1; d < 64; d <<= 1) {
        unsigned Al = __shfl_up(incA, d, 64);
        unsigned Bl = __shfl_up(incB, d, 64);
        if (lane >= d) {
            incA = incA | (Al & incB);
            incB = Bl & incB;
        }
    }
    unsigned pin = __shfl_up(incA, 1, 64);
    if (lane == 0) pin = 0u;

    // Recompute the 8 steps with the true incoming state
    unsigned p = pin, skipbits = 0u;
    int cnt = 0;
#pragma unroll
    for (int k = 0; k < 8; ++k) {
        unsigned a  = (toks[k] == SEP_ID) ? 1u : 0u;
        unsigned bb = (toks[k] == PAD_ID) ? 1u : 0u;
        unsigned skip = p & bb;
        skipbits |= skip << k;
        cnt += (int)skip;
        p = a | skip;
    }

    // Exclusive prefix sum of per-lane skip counts -> pad_num at lane start
    int pref = cnt;
    for (int d = 1; d < 64; d <<= 1) {
        int v = __shfl_up(pref, d, 64);
        if (lane >= d) pref += v;
    }
    pref -= cnt;

    int pad = pref;
#pragma unroll
    for (int k = 0; k < 8; ++k) {
        int s = s0 + k;
        unsigned skip = (skipbits >> k) & 1u;
        idx[s * B_SZ + b] = skip ? -1 : (s - pad);
        pad += (int)skip;
    }
}

// Kernel 2: fused gather+add. One wave owns 32 CONTIGUOUS rows. Per-row
// metadata (tok, pidx) is preloaded once (lanes 0-31: toks, lanes 32-63:
// pidx) and broadcast per-iteration via __shfl — removing the per-iter
// scalar-load latency from the critical path. tw[0] is exactly zero in the
// input (padding row), so no tok mask is needed.
__global__ void __launch_bounds__(NTHR)
emb_fused_kernel(const int* __restrict__ seq,
                 const float* __restrict__ tw,
                 const float* __restrict__ pe,
                 const int* __restrict__ idx,
                 float* __restrict__ out) {
    const unsigned t    = blockIdx.x * NTHR + threadIdx.x;
    const unsigned lane = t & 63u;
    const unsigned wave = t >> 6;
    const unsigned row0 = wave * ROWS_PER_WAVE;
    const unsigned doff = lane * 4u;

    // Preload 32 toks + 32 pidx for this wave's rows (one load per lane).
    int meta;
    if (lane < 32) meta = seq[row0 + lane];
    else           meta = idx[row0 + (lane - 32u)];

    float* orow = out + (size_t)row0 * D_DIM + doff;

#pragma unroll 8
    for (int it = 0; it < ROWS_PER_WAVE; ++it) {
        const int tok  = __shfl(meta, it, 64);
        const int pidx = __shfl(meta, it + 32, 64);

        const f32x4 tv = *(const f32x4*)(tw + (size_t)tok * D_DIM + doff);
        const int   pc = (pidx < 0) ? 0 : pidx;
        const f32x4 pv = *(const f32x4*)(pe + (size_t)pc * D_DIM + doff);
        const float pm = (pidx < 0) ? 0.0f : 1.0f;

        f32x4 o = tv + pv * pm;
        __builtin_nontemporal_store(o, (f32x4*)(orow + (size_t)it * D_DIM));
    }
}

extern "C" void kernel_launch(void* const* d_in, const int* in_sizes, int n_in,
                              void* d_out, int out_size, void* d_ws, size_t ws_size,
                              hipStream_t stream) {
    const int*   seq = (const int*)d_in[0];    // [S, B] int32
    const float* tw  = (const float*)d_in[1];  // [VOCAB, D] f32
    const float* pe  = (const float*)d_in[2];  // [MAX_LEN, D] f32
    float* out = (float*)d_out;                // [S, B, D] f32
    int*   idx = (int*)d_ws;                   // [S, B] int32 scratch (1 MiB)

    // 1) wave-parallel scan: 512 columns, 1 wave each -> 128 blocks x 256
    emb_scan_wave<<<dim3(B_SZ / 4), dim3(256), 0, stream>>>(seq, idx);

    // 2) fused gather+add: 8192 waves, 32 contiguous rows each
    emb_fused_kernel<<<dim3(NBLK), dim3(NTHR), 0, stream>>>(seq, tw, pe, idx, out);
}

// Round 5
// 53.839 us; speedup vs baseline: 1.5972x; 1.0993x over previous
//
#include <hip/hip_runtime.h>

// Problem constants (match reference file)
#define S_LEN 512
#define B_SZ  512
#define D_DIM 256
#define SEP_ID 13
#define PAD_ID 1

#define NTHR   256
#define ROWS_PER_WAVE 32
#define NROWS  (S_LEN * B_SZ)                         // 262144
#define NWAVE  (NROWS / ROWS_PER_WAVE)                // 8192 waves
#define NBLK   (NWAVE / (NTHR / 64))                  // 2048 blocks

typedef float f32x4 __attribute__((ext_vector_type(4)));

// Kernel 1: wave-parallel inner-padding state machine (unchanged).
__global__ void emb_scan_wave(const int* __restrict__ seq,
                              int* __restrict__ idx) {
    const int lane = threadIdx.x & 63;
    const int b = blockIdx.x * (blockDim.x >> 6) + (threadIdx.x >> 6);
    if (b >= B_SZ) return;

    const int s0 = lane * (S_LEN / 64);      // 8 positions per lane
    int toks[8];
#pragma unroll
    for (int k = 0; k < 8; ++k) toks[k] = seq[(s0 + k) * B_SZ + b];

    // Local transfer function over this lane's 8 tokens: f(p) = A | (p & B)
    unsigned A = 0u, Bf = 1u;
#pragma unroll
    for (int k = 0; k < 8; ++k) {
        unsigned a  = (toks[k] == SEP_ID) ? 1u : 0u;
        unsigned bb = (toks[k] == PAD_ID) ? 1u : 0u;
        A  = a | (A & bb);
        Bf = Bf & bb;
    }

    // Inclusive Kogge-Stone scan of function composition (lower lanes first)
    unsigned incA = A, incB = Bf;
    for (int d = 1; d < 64; d <<= 1) {
        unsigned Al = __shfl_up(incA, d, 64);
        unsigned Bl = __shfl_up(incB, d, 64);
        if (lane >= d) {
            incA = incA | (Al & incB);
            incB = Bl & incB;
        }
    }
    unsigned pin = __shfl_up(incA, 1, 64);
    if (lane == 0) pin = 0u;

    // Recompute the 8 steps with the true incoming state
    unsigned p = pin, skipbits = 0u;
    int cnt = 0;
#pragma unroll
    for (int k = 0; k < 8; ++k) {
        unsigned a  = (toks[k] == SEP_ID) ? 1u : 0u;
        unsigned bb = (toks[k] == PAD_ID) ? 1u : 0u;
        unsigned skip = p & bb;
        skipbits |= skip << k;
        cnt += (int)skip;
        p = a | skip;
    }

    // Exclusive prefix sum of per-lane skip counts -> pad_num at lane start
    int pref = cnt;
    for (int d = 1; d < 64; d <<= 1) {
        int v = __shfl_up(pref, d, 64);
        if (lane >= d) pref += v;
    }
    pref -= cnt;

    int pad = pref;
#pragma unroll
    for (int k = 0; k < 8; ++k) {
        int s = s0 + k;
        unsigned skip = (skipbits >> k) & 1u;
        idx[s * B_SZ + b] = skip ? -1 : (s - pad);
        pad += (int)skip;
    }
}

// Kernel 2: fused gather+add — IDENTICAL to R4 except plain (write-back)
// stores instead of nontemporal: A/B test of the nt flag's effect on DRAM
// write efficiency vs L2 gather-set protection.
__global__ void __launch_bounds__(NTHR)
emb_fused_kernel(const int* __restrict__ seq,
                 const float* __restrict__ tw,
                 const float* __restrict__ pe,
                 const int* __restrict__ idx,
                 float* __restrict__ out) {
    const unsigned t    = blockIdx.x * NTHR + threadIdx.x;
    const unsigned lane = t & 63u;
    const unsigned wave = t >> 6;
    const unsigned row0 = wave * ROWS_PER_WAVE;
    const unsigned doff = lane * 4u;

    // Preload 32 toks + 32 pidx for this wave's rows (one load per lane).
    int meta;
    if (lane < 32) meta = seq[row0 + lane];
    else           meta = idx[row0 + (lane - 32u)];

    float* orow = out + (size_t)row0 * D_DIM + doff;

#pragma unroll 8
    for (int it = 0; it < ROWS_PER_WAVE; ++it) {
        const int tok  = __shfl(meta, it, 64);
        const int pidx = __shfl(meta, it + 32, 64);

        const f32x4 tv = *(const f32x4*)(tw + (size_t)tok * D_DIM + doff);
        const int   pc = (pidx < 0) ? 0 : pidx;
        const f32x4 pv = *(const f32x4*)(pe + (size_t)pc * D_DIM + doff);
        const float pm = (pidx < 0) ? 0.0f : 1.0f;

        f32x4 o = tv + pv * pm;
        *(f32x4*)(orow + (size_t)it * D_DIM) = o;
    }
}

extern "C" void kernel_launch(void* const* d_in, const int* in_sizes, int n_in,
                              void* d_out, int out_size, void* d_ws, size_t ws_size,
                              hipStream_t stream) {
    const int*   seq = (const int*)d_in[0];    // [S, B] int32
    const float* tw  = (const float*)d_in[1];  // [VOCAB, D] f32
    const float* pe  = (const float*)d_in[2];  // [MAX_LEN, D] f32
    float* out = (float*)d_out;                // [S, B, D] f32
    int*   idx = (int*)d_ws;                   // [S, B] int32 scratch (1 MiB)

    // 1) wave-parallel scan: 512 columns, 1 wave each -> 128 blocks x 256
    emb_scan_wave<<<dim3(B_SZ / 4), dim3(256), 0, stream>>>(seq, idx);

    // 2) fused gather+add: 8192 waves, 32 contiguous rows each
    emb_fused_kernel<<<dim3(NBLK), dim3(NTHR), 0, stream>>>(seq, tw, pe, idx, out);
}

// Round 6
// 53.398 us; speedup vs baseline: 1.6104x; 1.0083x over previous
//
#include <hip/hip_runtime.h>

// Problem constants (match reference file)
#define S_LEN 512
#define B_SZ  512
#define D_DIM 256
#define SEP_ID 13
#define PAD_ID 1

#define NTHR   256
#define ROWS_PER_WAVE 32
#define ROWS_PER_BLOCK 128                            // 4 waves x 32 rows
#define NROWS  (S_LEN * B_SZ)                         // 262144
#define NBLK   (NROWS / ROWS_PER_BLOCK)               // 2048 blocks

typedef float f32x4 __attribute__((ext_vector_type(4)));

// Kernel 1: wave-parallel inner-padding state machine (unchanged).
__global__ void emb_scan_wave(const int* __restrict__ seq,
                              int* __restrict__ idx) {
    const int lane = threadIdx.x & 63;
    const int b = blockIdx.x * (blockDim.x >> 6) + (threadIdx.x >> 6);
    if (b >= B_SZ) return;

    const int s0 = lane * (S_LEN / 64);      // 8 positions per lane
    int toks[8];
#pragma unroll
    for (int k = 0; k < 8; ++k) toks[k] = seq[(s0 + k) * B_SZ + b];

    // Local transfer function over this lane's 8 tokens: f(p) = A | (p & B)
    unsigned A = 0u, Bf = 1u;
#pragma unroll
    for (int k = 0; k < 8; ++k) {
        unsigned a  = (toks[k] == SEP_ID) ? 1u : 0u;
        unsigned bb = (toks[k] == PAD_ID) ? 1u : 0u;
        A  = a | (A & bb);
        Bf = Bf & bb;
    }

    // Inclusive Kogge-Stone scan of function composition (lower lanes first)
    unsigned incA = A, incB = Bf;
    for (int d = 1; d < 64; d <<= 1) {
        unsigned Al = __shfl_up(incA, d, 64);
        unsigned Bl = __shfl_up(incB, d, 64);
        if (lane >= d) {
            incA = incA | (Al & incB);
            incB = Bl & incB;
        }
    }
    unsigned pin = __shfl_up(incA, 1, 64);
    if (lane == 0) pin = 0u;

    // Recompute the 8 steps with the true incoming state
    unsigned p = pin, skipbits = 0u;
    int cnt = 0;
#pragma unroll
    for (int k = 0; k < 8; ++k) {
        unsigned a  = (toks[k] == SEP_ID) ? 1u : 0u;
        unsigned bb = (toks[k] == PAD_ID) ? 1u : 0u;
        unsigned skip = p & bb;
        skipbits |= skip << k;
        cnt += (int)skip;
        p = a | skip;
    }

    // Exclusive prefix sum of per-lane skip counts -> pad_num at lane start
    int pref = cnt;
    for (int d = 1; d < 64; d <<= 1) {
        int v = __shfl_up(pref, d, 64);
        if (lane >= d) pref += v;
    }
    pref -= cnt;

    int pad = pref;
#pragma unroll
    for (int k = 0; k < 8; ++k) {
        int s = s0 + k;
        unsigned skip = (skipbits >> k) & 1u;
        idx[s * B_SZ + b] = skip ? -1 : (s - pad);
        pad += (int)skip;
    }
}

// Kernel 2: fused gather+add with SCALAR metadata loads.
// Block owns 128 contiguous rows; wave wid owns rows [wid*32, wid*32+32).
// wid is forced into an SGPR via readfirstlane, so seq/idx loads at
// compile-time-constant offsets have fully wave-uniform addresses -> the
// backend emits s_load through the constant cache. No DS ops, no shfl;
// gather addresses are SGPR-base + lane offset.
__global__ void __launch_bounds__(NTHR)
emb_fused_kernel(const int* __restrict__ seq,
                 const float* __restrict__ tw,
                 const float* __restrict__ pe,
                 const int* __restrict__ idx,
                 float* __restrict__ out) {
    const unsigned lane  = threadIdx.x & 63u;
    const unsigned wid_s = (unsigned)__builtin_amdgcn_readfirstlane(threadIdx.x >> 6);
    const unsigned row0  = blockIdx.x * ROWS_PER_BLOCK + wid_s * ROWS_PER_WAVE;
    const unsigned doff  = lane * 4u;

    const int* __restrict__ tokp  = seq + row0;   // wave-uniform pointers
    const int* __restrict__ pidxp = idx + row0;
    float* orow = out + (size_t)row0 * D_DIM + doff;

#pragma unroll 8
    for (int it = 0; it < ROWS_PER_WAVE; ++it) {
        const int tok  = tokp[it];    // uniform addr -> s_load
        const int pidx = pidxp[it];   // uniform addr -> s_load

        const f32x4 tv = *(const f32x4*)(tw + (size_t)tok * D_DIM + doff);
        const int   pc = (pidx < 0) ? 0 : pidx;
        const f32x4 pv = *(const f32x4*)(pe + (size_t)pc * D_DIM + doff);
        const float pm = (pidx < 0) ? 0.0f : 1.0f;

        f32x4 o = tv + pv * pm;
        *(f32x4*)(orow + (size_t)it * D_DIM) = o;
    }
}

extern "C" void kernel_launch(void* const* d_in, const int* in_sizes, int n_in,
                              void* d_out, int out_size, void* d_ws, size_t ws_size,
                              hipStream_t stream) {
    const int*   seq = (const int*)d_in[0];    // [S, B] int32
    const float* tw  = (const float*)d_in[1];  // [VOCAB, D] f32
    const float* pe  = (const float*)d_in[2];  // [MAX_LEN, D] f32
    float* out = (float*)d_out;                // [S, B, D] f32
    int*   idx = (int*)d_ws;                   // [S, B] int32 scratch (1 MiB)

    // 1) wave-parallel scan: 512 columns, 1 wave each -> 128 blocks x 256
    emb_scan_wave<<<dim3(B_SZ / 4), dim3(256), 0, stream>>>(seq, idx);

    // 2) fused gather+add: 2048 blocks x 256, 128 contiguous rows per block
    emb_fused_kernel<<<dim3(NBLK), dim3(NTHR), 0, stream>>>(seq, tw, pe, idx, out);
}